// Round 1
// baseline (130.881 us; speedup 1.0000x reference)
//
#include <hip/hip_runtime.h>
#include <math.h>

// RBF network, fully fused: x[8192,32] -> RBF(512,d32) -> Lin(64) -> RBF(512,d64) -> Lin(32)
// One kernel; each block owns R=16 rows; params staged per 128-center pass into an LDS union buffer.

#define NROWS 8192
#define D0 32
#define D1 64
#define J0 64
#define J1 32
#define CTOT 512
#define R 16
#define CT 128
#define NPASS (CTOT / CT)
#define BLOCK 256

__global__ __launch_bounds__(BLOCK, 2)
void rbfnet_fused(const float* __restrict__ x,
                  const float* __restrict__ centers0, const float* __restrict__ ls0,
                  const float* __restrict__ W0, const float* __restrict__ b0,
                  const float* __restrict__ centers1, const float* __restrict__ ls1,
                  const float* __restrict__ W1, const float* __restrict__ b1,
                  float* __restrict__ out)
{
    // LDS: x rows (2KB) + h rows (4.25KB, pad 68 for conflict-free norm pass + aligned b128)
    // + row norms + phi tile (8KB) + 33KB union staging buffer (centers-tile / W-tile alternate)
    __shared__ float x_lds[R * D0];
    __shared__ float h_lds[R * 68];
    __shared__ float rn_lds[R];
    __shared__ float hn_lds[R];
    __shared__ float phi_lds[R * CT];
    __shared__ float stage[8448];

    const int t = threadIdx.x;
    const int row0 = blockIdx.x * R;

    // ---- stage x rows (coalesced) ----
    for (int i = t; i < R * D0; i += BLOCK) x_lds[i] = x[row0 * D0 + i];
    __syncthreads();
    if (t < R) {
        float s = 0.f;
        #pragma unroll
        for (int d = 0; d < D0; ++d) { float v = x_lds[t * D0 + d]; s += v * v; }
        rn_lds[t] = s;
    }

    // RBF mapping: thread -> center cl in tile, row-half rh (8 rows each)
    const int cl = t & (CT - 1);
    const int rh = t >> 7;
    // GEMM0 mapping: thread -> output column j0, row group rg0 (4 rows each)
    const int j0 = t & 63;
    const int rg0 = t >> 6;
    float acc0[4] = {0.f, 0.f, 0.f, 0.f};

    // ================= layer 0 =================
    for (int pass = 0; pass < NPASS; ++pass) {
        const int cbase = pass * CT;
        __syncthreads();  // prior GEMM reads of stage done (and rn ready on pass 0)

        // stage centers0 tile transposed: stage[d*131 + c]  (writes <=2-way, reads conflict-free)
        for (int i = t; i < CT * D0; i += BLOCK) {
            int c = i >> 5, d = i & 31;
            stage[d * 131 + c] = centers0[(cbase + c) * D0 + d];
        }
        __syncthreads();

        // RBF: phi[r][cl] = exp(-(||x||^2+||c||^2-2 x.c) * exp(-2*ls))
        {
            float creg[D0];
            #pragma unroll
            for (int d = 0; d < D0; ++d) creg[d] = stage[d * 131 + cl];
            float cn = 0.f;
            #pragma unroll
            for (int d = 0; d < D0; ++d) cn += creg[d] * creg[d];
            const float iv = __expf(-2.0f * ls0[cbase + cl]);
            for (int rr = 0; rr < 8; ++rr) {
                const int r = rh * 8 + rr;
                float dot = 0.f;
                #pragma unroll
                for (int d4 = 0; d4 < D0 / 4; ++d4) {
                    const float4 xv = *(const float4*)&x_lds[r * D0 + 4 * d4];
                    dot += xv.x * creg[4 * d4] + xv.y * creg[4 * d4 + 1]
                         + xv.z * creg[4 * d4 + 2] + xv.w * creg[4 * d4 + 3];
                }
                const float m = 2.f * dot - rn_lds[r] - cn;
                phi_lds[r * CT + cl] = __expf(m * iv);
            }
        }
        __syncthreads();

        // stage W0 tile transposed: stage[c*65 + j]  (write & read conflict-free)
        for (int i = t; i < J0 * CT; i += BLOCK) {
            int j = i >> 7, c = i & 127;
            stage[c * 65 + j] = W0[j * CTOT + cbase + c];
        }
        __syncthreads();

        // GEMM0 accumulate: h[r][j0] += sum_c phi[r][c] * W0[j0][c]
        for (int c4 = 0; c4 < CT / 4; ++c4) {
            const float w0v = stage[(4 * c4 + 0) * 65 + j0];
            const float w1v = stage[(4 * c4 + 1) * 65 + j0];
            const float w2v = stage[(4 * c4 + 2) * 65 + j0];
            const float w3v = stage[(4 * c4 + 3) * 65 + j0];
            #pragma unroll
            for (int rr = 0; rr < 4; ++rr) {
                const float4 p = *(const float4*)&phi_lds[(rg0 * 4 + rr) * CT + 4 * c4];
                acc0[rr] += w0v * p.x + w1v * p.y + w2v * p.z + w3v * p.w;
            }
        }
    }

    // write h to LDS (pad-68 rows)
    {
        const float bj = b0[j0];
        #pragma unroll
        for (int rr = 0; rr < 4; ++rr)
            h_lds[(rg0 * 4 + rr) * 68 + j0] = acc0[rr] + bj;
    }
    __syncthreads();
    if (t < R) {
        float s = 0.f;
        #pragma unroll
        for (int d = 0; d < D1; ++d) { float v = h_lds[t * 68 + d]; s += v * v; }
        hn_lds[t] = s;
    }

    // GEMM1 mapping: j1 in 0..31, rg1 in 0..7 (2 rows each)
    const int j1 = t & 31;
    const int rg1 = t >> 5;
    float acc1[2] = {0.f, 0.f};

    // ================= layer 1 =================
    for (int pass = 0; pass < NPASS; ++pass) {
        const int cbase = pass * CT;
        __syncthreads();  // prior GEMM done / hn ready on pass 0

        // stage centers1 tile transposed: stage[d*131 + c]
        for (int i = t; i < CT * D1; i += BLOCK) {
            int c = i >> 6, d = i & 63;
            stage[d * 131 + c] = centers1[(cbase + c) * D1 + d];
        }
        __syncthreads();

        // RBF layer 1 on h rows
        {
            float creg[D1];
            #pragma unroll
            for (int d = 0; d < D1; ++d) creg[d] = stage[d * 131 + cl];
            float cn = 0.f;
            #pragma unroll
            for (int d = 0; d < D1; ++d) cn += creg[d] * creg[d];
            const float iv = __expf(-2.0f * ls1[cbase + cl]);
            for (int rr = 0; rr < 8; ++rr) {
                const int r = rh * 8 + rr;
                float dot = 0.f;
                #pragma unroll
                for (int d4 = 0; d4 < D1 / 4; ++d4) {
                    const float4 xv = *(const float4*)&h_lds[r * 68 + 4 * d4];
                    dot += xv.x * creg[4 * d4] + xv.y * creg[4 * d4 + 1]
                         + xv.z * creg[4 * d4 + 2] + xv.w * creg[4 * d4 + 3];
                }
                const float m = 2.f * dot - hn_lds[r] - cn;
                phi_lds[r * CT + cl] = __expf(m * iv);
            }
        }
        __syncthreads();

        // stage W1 tile transposed: stage[c*33 + j]
        for (int i = t; i < J1 * CT; i += BLOCK) {
            int j = i >> 7, c = i & 127;
            stage[c * 33 + j] = W1[j * CTOT + cbase + c];
        }
        __syncthreads();

        // GEMM1 accumulate
        for (int c4 = 0; c4 < CT / 4; ++c4) {
            const float w0v = stage[(4 * c4 + 0) * 33 + j1];
            const float w1v = stage[(4 * c4 + 1) * 33 + j1];
            const float w2v = stage[(4 * c4 + 2) * 33 + j1];
            const float w3v = stage[(4 * c4 + 3) * 33 + j1];
            #pragma unroll
            for (int rr = 0; rr < 2; ++rr) {
                const float4 p = *(const float4*)&phi_lds[(rg1 * 2 + rr) * CT + 4 * c4];
                acc1[rr] += w0v * p.x + w1v * p.y + w2v * p.z + w3v * p.w;
            }
        }
    }

    // ---- epilogue: out[r][j1] = acc + b1 ----
    {
        const float bj = b1[j1];
        #pragma unroll
        for (int rr = 0; rr < 2; ++rr) {
            const int r = rg1 * 2 + rr;
            out[(row0 + r) * J1 + j1] = acc1[rr] + bj;
        }
    }
}

extern "C" void kernel_launch(void* const* d_in, const int* in_sizes, int n_in,
                              void* d_out, int out_size, void* d_ws, size_t ws_size,
                              hipStream_t stream) {
    const float* xin = (const float*)d_in[0];
    const float* c0  = (const float*)d_in[1];
    const float* ls0 = (const float*)d_in[2];
    const float* W0  = (const float*)d_in[3];
    const float* b0  = (const float*)d_in[4];
    const float* c1  = (const float*)d_in[5];
    const float* ls1 = (const float*)d_in[6];
    const float* W1  = (const float*)d_in[7];
    const float* b1  = (const float*)d_in[8];
    float* outp = (float*)d_out;

    dim3 grid(NROWS / R);   // 512 blocks
    dim3 block(BLOCK);      // 256 threads
    hipLaunchKernelGGL(rbfnet_fused, grid, block, 0, stream,
                       xin, c0, ls0, W0, b0, c1, ls1, W1, b1, outp);
}

// Round 2
// 118.983 us; speedup vs baseline: 1.1000x; 1.1000x over previous
//
#include <hip/hip_runtime.h>
#include <math.h>

// x[8192,32] -> RBF(512,d32) -> Lin(64) -> RBF(512,d64) -> Lin(32)
// 512 threads/block, 16 rows/block, grid 512. lane<->center for RBF (centers in
// registers, row broadcast from LDS); lane<->output-col for GEMMs (W prepacked
// in d_ws for coalesced global b128, phi via LDS broadcast, split-K + LDS reduce).

#define NROWS 8192
#define R 16
#define BLOCK 512
#define GRID (NROWS / R)

// ---- prepack W0[64][512] -> wp0[c4][64][4], W1[32][512] -> wp1[c4][32][4] ----
__global__ void prepack_w(const float* __restrict__ W0, const float* __restrict__ W1,
                          float* __restrict__ wp0, float* __restrict__ wp1) {
    int i = blockIdx.x * 256 + threadIdx.x;
    if (i < 64 * 512) {
        int j = i >> 9, c = i & 511;
        wp0[((c >> 2) * 64 + j) * 4 + (c & 3)] = W0[i];
    } else {
        int k = i - 64 * 512;
        if (k < 32 * 512) {
            int j = k >> 9, c = k & 511;
            wp1[((c >> 2) * 32 + j) * 4 + (c & 3)] = W1[k];
        }
    }
}

template <int PACKED>
__global__ __launch_bounds__(BLOCK, 4)
void rbfnet(const float* __restrict__ x,
            const float* __restrict__ c0p, const float* __restrict__ ls0,
            const float* __restrict__ W0, const float* __restrict__ b0,
            const float* __restrict__ c1p, const float* __restrict__ ls1,
            const float* __restrict__ W1, const float* __restrict__ b1,
            const float* __restrict__ wp0, const float* __restrict__ wp1,
            float* __restrict__ out)
{
    __shared__ float x_lds[R][32];          // 2 KB
    __shared__ float h_lds[R][68];          // 4.25 KB (pad 68: 272B rows, 16B aligned)
    __shared__ float phi[R][512];           // 32 KB (phi0, reused as phi1)
    __shared__ float rn[R], hn[R];
    __shared__ float hpart[8][R][64];       // 32 KB (L0 split-K partials; reused for L1: [w][r][j1<32])

    const int t = threadIdx.x;
    const int lane = t & 63;
    const int w = t >> 6;
    const int row0 = blockIdx.x * R;

    // ---- stage x rows (512 floats == 512 threads), row norms ----
    x_lds[t >> 5][t & 31] = x[row0 * 32 + t];
    __syncthreads();
    if (t < R) {
        float s = 0.f;
        for (int d = 0; d < 32; ++d) { float v = x_lds[t][(d + t) & 31]; s += v * v; }
        rn[t] = s;
    }
    __syncthreads();

    // ================= RBF0: lane ci = t owns center ci =================
    const int ci = t;
    {
        float creg[32];
        #pragma unroll
        for (int d4 = 0; d4 < 8; ++d4) {
            float4 v = *(const float4*)&c0p[ci * 32 + d4 * 4];
            creg[4 * d4] = v.x; creg[4 * d4 + 1] = v.y; creg[4 * d4 + 2] = v.z; creg[4 * d4 + 3] = v.w;
        }
        float cn = 0.f;
        #pragma unroll
        for (int d = 0; d < 32; ++d) cn += creg[d] * creg[d];
        const float iv = __expf(-2.0f * ls0[ci]);

        for (int r = 0; r < R; ++r) {
            float d0 = 0.f, d1 = 0.f, d2 = 0.f, d3 = 0.f;
            #pragma unroll
            for (int d4 = 0; d4 < 8; ++d4) {
                float4 xv = *(const float4*)&x_lds[r][d4 * 4];   // wave-uniform broadcast
                d0 += xv.x * creg[4 * d4];
                d1 += xv.y * creg[4 * d4 + 1];
                d2 += xv.z * creg[4 * d4 + 2];
                d3 += xv.w * creg[4 * d4 + 3];
            }
            float dot = (d0 + d1) + (d2 + d3);
            phi[r][ci] = __expf((2.f * dot - rn[r] - cn) * iv);
        }
    }
    __syncthreads();

    // ================= GEMM-L0: h[16][64], K split 8 ways by wave =================
    // wave w handles c4 in [w*16, w*16+16); lane = output col j; acc over all 16 rows
    {
        const int j = lane;
        float acc[R];
        #pragma unroll
        for (int r = 0; r < R; ++r) acc[r] = 0.f;

        const int c4base = w * 16;
        #pragma unroll 2
        for (int i = 0; i < 16; ++i) {
            const int c4 = c4base + i;
            float4 wv = PACKED ? *(const float4*)&wp0[(c4 * 64 + j) * 4]
                               : *(const float4*)&W0[j * 512 + c4 * 4];
            #pragma unroll
            for (int r = 0; r < R; ++r) {
                float4 p = *(const float4*)&phi[r][c4 * 4];      // broadcast
                acc[r] += wv.x * p.x + wv.y * p.y + wv.z * p.z + wv.w * p.w;
            }
        }
        #pragma unroll
        for (int r = 0; r < R; ++r) hpart[w][r][j] = acc[r];
    }
    __syncthreads();
    // reduce split-K partials -> h_lds (each thread: 2 outputs)
    {
        const int j = t & 63;
        const float bj = b0[j];
        #pragma unroll
        for (int rr = 0; rr < 2; ++rr) {
            const int r = (t >> 6) + rr * 8;
            float s = 0.f;
            #pragma unroll
            for (int k = 0; k < 8; ++k) s += hpart[k][r][j];
            h_lds[r][j] = s + bj;
        }
    }
    __syncthreads();
    if (t < R) {
        float s = 0.f;
        for (int d = 0; d < 64; ++d) { float v = h_lds[t][(d + t) & 63]; s += v * v; }
        hn[t] = s;
    }
    __syncthreads();

    // ================= RBF1: lane ci owns center ci (d=64) =================
    {
        float creg1[64];
        #pragma unroll
        for (int d4 = 0; d4 < 16; ++d4) {
            float4 v = *(const float4*)&c1p[ci * 64 + d4 * 4];
            creg1[4 * d4] = v.x; creg1[4 * d4 + 1] = v.y; creg1[4 * d4 + 2] = v.z; creg1[4 * d4 + 3] = v.w;
        }
        float cn1 = 0.f;
        #pragma unroll
        for (int d = 0; d < 64; ++d) cn1 += creg1[d] * creg1[d];
        const float iv1 = __expf(-2.0f * ls1[ci]);

        for (int r = 0; r < R; ++r) {
            float d0 = 0.f, d1 = 0.f, d2 = 0.f, d3 = 0.f;
            #pragma unroll
            for (int d4 = 0; d4 < 16; ++d4) {
                float4 hv = *(const float4*)&h_lds[r][d4 * 4];   // broadcast
                d0 += hv.x * creg1[4 * d4];
                d1 += hv.y * creg1[4 * d4 + 1];
                d2 += hv.z * creg1[4 * d4 + 2];
                d3 += hv.w * creg1[4 * d4 + 3];
            }
            float dot = (d0 + d1) + (d2 + d3);
            phi[r][ci] = __expf((2.f * dot - hn[r] - cn1) * iv1);   // overwrite phi0
        }
    }
    __syncthreads();

    // ================= GEMM-L1: out[16][32], K split 16 ways (8 waves x 2 half-waves) ====
    // wave w, half kh: c4 in [w*16 + kh*8, +8); lane j1 = lane&31; acc over 16 rows
    {
        const int j1 = lane & 31;
        const int kh = lane >> 5;
        float acc[R];
        #pragma unroll
        for (int r = 0; r < R; ++r) acc[r] = 0.f;

        const int c4base = w * 16 + kh * 8;
        #pragma unroll 2
        for (int i = 0; i < 8; ++i) {
            const int c4 = c4base + i;
            float4 wv = PACKED ? *(const float4*)&wp1[(c4 * 32 + j1) * 4]
                               : *(const float4*)&W1[j1 * 512 + c4 * 4];
            #pragma unroll
            for (int r = 0; r < R; ++r) {
                float4 p = *(const float4*)&phi[r][c4 * 4];      // 2-addr broadcast
                acc[r] += wv.x * p.x + wv.y * p.y + wv.z * p.z + wv.w * p.w;
            }
        }
        // fold the two half-wave K-partials
        #pragma unroll
        for (int r = 0; r < R; ++r) acc[r] += __shfl_xor(acc[r], 32, 64);
        if (kh == 0) {
            #pragma unroll
            for (int r = 0; r < R; ++r) hpart[w][r][j1] = acc[r];  // reuse hpart as pp
        }
    }
    __syncthreads();
    // final reduce over 8 wave-partials + bias, coalesced store (512 outputs == 512 threads)
    {
        const int r = t >> 5;
        const int j = t & 31;
        float s = 0.f;
        #pragma unroll
        for (int k = 0; k < 8; ++k) s += hpart[k][r][j];
        out[(row0 + r) * 32 + j] = s + b1[j];
    }
}

extern "C" void kernel_launch(void* const* d_in, const int* in_sizes, int n_in,
                              void* d_out, int out_size, void* d_ws, size_t ws_size,
                              hipStream_t stream) {
    const float* xin = (const float*)d_in[0];
    const float* c0  = (const float*)d_in[1];
    const float* ls0 = (const float*)d_in[2];
    const float* W0  = (const float*)d_in[3];
    const float* b0  = (const float*)d_in[4];
    const float* c1  = (const float*)d_in[5];
    const float* ls1 = (const float*)d_in[6];
    const float* W1  = (const float*)d_in[7];
    const float* b1  = (const float*)d_in[8];
    float* outp = (float*)d_out;

    const size_t need = (size_t)(64 * 512 + 32 * 512) * sizeof(float);  // 192 KB
    if (ws_size >= need && d_ws != nullptr) {
        float* wp0 = (float*)d_ws;
        float* wp1 = wp0 + 64 * 512;
        hipLaunchKernelGGL(prepack_w, dim3(192), dim3(256), 0, stream, W0, W1, wp0, wp1);
        hipLaunchKernelGGL((rbfnet<1>), dim3(GRID), dim3(BLOCK), 0, stream,
                           xin, c0, ls0, W0, b0, c1, ls1, W1, b1, wp0, wp1, outp);
    } else {
        hipLaunchKernelGGL((rbfnet<0>), dim3(GRID), dim3(BLOCK), 0, stream,
                           xin, c0, ls0, W0, b0, c1, ls1, W1, b1,
                           (const float*)nullptr, (const float*)nullptr, outp);
    }
}

// Round 3
// 108.632 us; speedup vs baseline: 1.2048x; 1.0953x over previous
//
#include <hip/hip_runtime.h>
#include <math.h>

// x[8192,32] -> RBF(512,d32) -> Lin(64) -> RBF(512,d64) -> Lin(32)
// 512 threads/block, 16 rows/block, grid 512 (2 blocks/CU, all resident).
// RBF: lane<->center, center chunks of 16 dims in regs (live set bounded ~40 VGPR
// to prevent the round-2 rematerialization blowup), row broadcast from LDS.
// GEMM: lane<->output col, split-K across waves, prepacked W (coalesced 1KB/instr),
// phi via uniform LDS broadcast, partials reduced through LDS once.

#define NROWS 8192
#define R 16
#define BLOCK 512
#define GRID (NROWS / R)

// ---- prepack W0[64][512] -> wp0[c4][64][4], W1[32][512] -> wp1[c4][32][4] ----
__global__ void prepack_w(const float* __restrict__ W0, const float* __restrict__ W1,
                          float* __restrict__ wp0, float* __restrict__ wp1) {
    int i = blockIdx.x * 256 + threadIdx.x;
    if (i < 64 * 512) {
        int j = i >> 9, c = i & 511;
        wp0[((c >> 2) * 64 + j) * 4 + (c & 3)] = W0[i];
    } else {
        int k = i - 64 * 512;
        if (k < 32 * 512) {
            int j = k >> 9, c = k & 511;
            wp1[((c >> 2) * 32 + j) * 4 + (c & 3)] = W1[k];
        }
    }
}

template <int PACKED>
__global__ __launch_bounds__(BLOCK, 4)
void rbfnet(const float* __restrict__ x,
            const float* __restrict__ c0p, const float* __restrict__ ls0,
            const float* __restrict__ W0, const float* __restrict__ b0,
            const float* __restrict__ c1p, const float* __restrict__ ls1,
            const float* __restrict__ W1, const float* __restrict__ b1,
            const float* __restrict__ wp0, const float* __restrict__ wp1,
            float* __restrict__ out)
{
    __shared__ float x_lds[R][32];          // 2 KB
    __shared__ float h_lds[R][68];          // 4.25 KB
    __shared__ float phi[R][512];           // 32 KB (phi0, reused as phi1)
    __shared__ float rn[R], hn[R];
    __shared__ float hpart[8][R][64];       // 32 KB split-K partials (reused by GEMM1)

    const int t = threadIdx.x;
    const int lane = t & 63;
    const int w = t >> 6;
    const int row0 = blockIdx.x * R;

    // ---- stage x rows (512 floats == 512 threads) ----
    x_lds[t >> 5][t & 31] = x[row0 * 32 + t];
    __syncthreads();

    // ---- rn: 32 threads per row, shfl tree ----
    {
        const int r = t >> 5, d = t & 31;
        float v = x_lds[r][d];
        float s = v * v;
        s += __shfl_xor(s, 1);  s += __shfl_xor(s, 2);  s += __shfl_xor(s, 4);
        s += __shfl_xor(s, 8);  s += __shfl_xor(s, 16);
        if (d == 0) rn[r] = s;
    }
    __syncthreads();

    const int ci = t;   // lane <-> center for both RBF layers

    // ================= RBF0 (d=32, 2 chunks of 16 dims) =================
    {
        float dot[R];
        #pragma unroll
        for (int r = 0; r < R; ++r) dot[r] = 0.f;
        float cn = 0.f;

        #pragma unroll
        for (int ch = 0; ch < 2; ++ch) {
            float c[16];
            #pragma unroll
            for (int q = 0; q < 4; ++q) {
                float4 v = *(const float4*)&c0p[ci * 32 + ch * 16 + q * 4];
                c[q * 4] = v.x; c[q * 4 + 1] = v.y; c[q * 4 + 2] = v.z; c[q * 4 + 3] = v.w;
            }
            #pragma unroll
            for (int q = 0; q < 16; ++q) cn += c[q] * c[q];
            #pragma unroll
            for (int r = 0; r < R; ++r) {
                float a0 = 0.f, a1 = 0.f, a2 = 0.f, a3 = 0.f;
                #pragma unroll
                for (int q = 0; q < 4; ++q) {
                    float4 xv = *(const float4*)&x_lds[r][ch * 16 + q * 4];  // broadcast
                    a0 += xv.x * c[q * 4];     a1 += xv.y * c[q * 4 + 1];
                    a2 += xv.z * c[q * 4 + 2]; a3 += xv.w * c[q * 4 + 3];
                }
                dot[r] += (a0 + a1) + (a2 + a3);
            }
        }
        const float iv = __expf(-2.0f * ls0[ci]);
        #pragma unroll
        for (int r = 0; r < R; ++r)
            phi[r][ci] = __expf((2.f * dot[r] - rn[r] - cn) * iv);
    }
    __syncthreads();

    // ================= GEMM-L0: h[16][64], split-K 8 ways by wave =================
    {
        const int j = lane;
        float acc[R];
        #pragma unroll
        for (int r = 0; r < R; ++r) acc[r] = 0.f;

        const int c4base = w * 16;
        #pragma unroll 2
        for (int i = 0; i < 16; ++i) {
            const int c4 = c4base + i;
            float4 wv = PACKED ? *(const float4*)&wp0[(c4 * 64 + j) * 4]
                               : *(const float4*)&W0[j * 512 + c4 * 4];
            #pragma unroll
            for (int r = 0; r < R; ++r) {
                float4 p = *(const float4*)&phi[r][c4 * 4];      // broadcast
                acc[r] += wv.x * p.x + wv.y * p.y + wv.z * p.z + wv.w * p.w;
            }
        }
        #pragma unroll
        for (int r = 0; r < R; ++r) hpart[w][r][j] = acc[r];
    }
    __syncthreads();

    // reduce split-K partials -> h_lds (each thread: 2 outputs)
    {
        const int j = t & 63;
        const float bj = b0[j];
        #pragma unroll
        for (int rr = 0; rr < 2; ++rr) {
            const int r = (t >> 6) + rr * 8;
            float s = 0.f;
            #pragma unroll
            for (int k = 0; k < 8; ++k) s += hpart[k][r][j];
            h_lds[r][j] = s + bj;
        }
    }
    __syncthreads();

    // ---- hn: 32 threads per row (2 elems each), shfl tree ----
    {
        const int r = t >> 5, d = t & 31;
        float v0 = h_lds[r][d], v1 = h_lds[r][d + 32];
        float s = v0 * v0 + v1 * v1;
        s += __shfl_xor(s, 1);  s += __shfl_xor(s, 2);  s += __shfl_xor(s, 4);
        s += __shfl_xor(s, 8);  s += __shfl_xor(s, 16);
        if (d == 0) hn[r] = s;
    }
    __syncthreads();

    // ================= RBF1 (d=64, 4 chunks of 16 dims) =================
    {
        float dot[R];
        #pragma unroll
        for (int r = 0; r < R; ++r) dot[r] = 0.f;
        float cn = 0.f;

        #pragma unroll
        for (int ch = 0; ch < 4; ++ch) {
            float c[16];
            #pragma unroll
            for (int q = 0; q < 4; ++q) {
                float4 v = *(const float4*)&c1p[ci * 64 + ch * 16 + q * 4];
                c[q * 4] = v.x; c[q * 4 + 1] = v.y; c[q * 4 + 2] = v.z; c[q * 4 + 3] = v.w;
            }
            #pragma unroll
            for (int q = 0; q < 16; ++q) cn += c[q] * c[q];
            #pragma unroll
            for (int r = 0; r < R; ++r) {
                float a0 = 0.f, a1 = 0.f, a2 = 0.f, a3 = 0.f;
                #pragma unroll
                for (int q = 0; q < 4; ++q) {
                    float4 hv = *(const float4*)&h_lds[r][ch * 16 + q * 4];  // broadcast
                    a0 += hv.x * c[q * 4];     a1 += hv.y * c[q * 4 + 1];
                    a2 += hv.z * c[q * 4 + 2]; a3 += hv.w * c[q * 4 + 3];
                }
                dot[r] += (a0 + a1) + (a2 + a3);
            }
        }
        const float iv = __expf(-2.0f * ls1[ci]);
        #pragma unroll
        for (int r = 0; r < R; ++r)
            phi[r][ci] = __expf((2.f * dot[r] - hn[r] - cn) * iv);   // overwrite phi0
    }
    __syncthreads();

    // ================= GEMM-L1: out[16][32], split-K 16 ways (8 waves x 2 half-waves) ====
    {
        const int j1 = lane & 31;
        const int kh = lane >> 5;
        float acc[R];
        #pragma unroll
        for (int r = 0; r < R; ++r) acc[r] = 0.f;

        const int c4base = w * 16 + kh * 8;
        #pragma unroll 2
        for (int i = 0; i < 8; ++i) {
            const int c4 = c4base + i;
            float4 wv = PACKED ? *(const float4*)&wp1[(c4 * 32 + j1) * 4]
                               : *(const float4*)&W1[j1 * 512 + c4 * 4];
            #pragma unroll
            for (int r = 0; r < R; ++r) {
                float4 p = *(const float4*)&phi[r][c4 * 4];      // broadcast (2 addrs/wave)
                acc[r] += wv.x * p.x + wv.y * p.y + wv.z * p.z + wv.w * p.w;
            }
        }
        #pragma unroll
        for (int r = 0; r < R; ++r) acc[r] += __shfl_xor(acc[r], 32);
        if (kh == 0) {
            #pragma unroll
            for (int r = 0; r < R; ++r) hpart[w][r][j1] = acc[r];  // reuse hpart
        }
    }
    __syncthreads();

    // final reduce over 8 wave-partials + bias, coalesced store
    {
        const int r = t >> 5;
        const int j = t & 31;
        float s = 0.f;
        #pragma unroll
        for (int k = 0; k < 8; ++k) s += hpart[k][r][j];
        out[(row0 + r) * 32 + j] = s + b1[j];
    }
}

extern "C" void kernel_launch(void* const* d_in, const int* in_sizes, int n_in,
                              void* d_out, int out_size, void* d_ws, size_t ws_size,
                              hipStream_t stream) {
    const float* xin = (const float*)d_in[0];
    const float* c0  = (const float*)d_in[1];
    const float* ls0 = (const float*)d_in[2];
    const float* W0  = (const float*)d_in[3];
    const float* b0  = (const float*)d_in[4];
    const float* c1  = (const float*)d_in[5];
    const float* ls1 = (const float*)d_in[6];
    const float* W1  = (const float*)d_in[7];
    const float* b1  = (const float*)d_in[8];
    float* outp = (float*)d_out;

    const size_t need = (size_t)(64 * 512 + 32 * 512) * sizeof(float);  // 192 KB
    if (ws_size >= need && d_ws != nullptr) {
        float* wp0 = (float*)d_ws;
        float* wp1 = wp0 + 64 * 512;
        hipLaunchKernelGGL(prepack_w, dim3(192), dim3(256), 0, stream, W0, W1, wp0, wp1);
        hipLaunchKernelGGL((rbfnet<1>), dim3(GRID), dim3(BLOCK), 0, stream,
                           xin, c0, ls0, W0, b0, c1, ls1, W1, b1, wp0, wp1, outp);
    } else {
        hipLaunchKernelGGL((rbfnet<0>), dim3(GRID), dim3(BLOCK), 0, stream,
                           xin, c0, ls0, W0, b0, c1, ls1, W1, b1,
                           (const float*)nullptr, (const float*)nullptr, outp);
    }
}